// Round 3
// baseline (145.104 us; speedup 1.0000x reference)
//
#include <hip/hip_runtime.h>
#include <math.h>

// Problem constants (fixed by the reference):
#define B  64
#define D  256
#define E  512
#define ND 1024

#define MAGIC 0x13579BDF

// ws offsets (in 4-byte units). Flags are ints; the rest floats.
#define FLAG1_OFF 0       // [128] phase-1 done flags
#define FLAG2_OFF 128     // [256] phase-2 done flags
#define FLAG3_OFF 384     // [256] phase-3 done flags
#define C1P_OFF   640     // [2]   c1 partials
#define T1P_OFF   704     // [128] t1 partials
#define T2P_OFF   832     // [256] t2 partials
#define W_OFF     2048    // [B*E]  signed weights
#define Q_OFF     35072   // [E*E]  Gram Q = W'W

__global__ __launch_bounds__(256) void fused_k(const int* __restrict__ det,
                                               const int* __restrict__ pebz,
                                               const float* __restrict__ para,
                                               const float* __restrict__ kwz,
                                               float* __restrict__ ws,
                                               float* __restrict__ out) {
    int* wsi = (int*)ws;
    const int blk = blockIdx.x;   // 0..255
    const int tid = threadIdx.x;  // 0..255

    __shared__ float ldsT[64 * 65];        // phase-3 transpose tile (pad 65: 2-way, free)
    __shared__ float We[64 * 32];          // phase-2 W[:, e-tile]
    __shared__ float Wf[64 * 32];          // phase-2 W[:, f-tile]
    __shared__ int   drow[D];              // phase-1 det row
    __shared__ float red[256];

    const int I = blk >> 4, J = blk & 15;  // 64x64 kwz tile / 32x32 Q tile coords

    // ---------------- Phase 1: W[b][e], t1 partials, c1 partials ----------------
    if (blk < 128) {
        const int b = blk >> 1;
        const int e = (blk & 1) * 256 + tid;
        drow[tid] = det[b * D + tid];
        __syncthreads();
        float x = para[e];
        float p = 1.0f / (1.0f + expf(-x)) + 1e-20f;
        float w = p / (1.0f - p);
        int acc = 0;
        #pragma unroll 8
        for (int d = 0; d < D; ++d)
            acc += drow[d] & pebz[d * E + e];       // binary product == AND
        float wbe = (acc & 1) ? -w : w;
        ws[W_OFF + b * E + e] = wbe;
        // t1 partial: sum_e W[b][e] * (K[2e][2e]+K[2e+1][2e+1])
        float dd = kwz[(size_t)(2 * e) * ND + (2 * e)]
                 + kwz[(size_t)(2 * e + 1) * ND + (2 * e + 1)];
        red[tid] = wbe * dd;
        __syncthreads();
        for (int s = 128; s > 0; s >>= 1) {
            if (tid < s) red[tid] += red[tid + s];
            __syncthreads();
        }
        if (tid == 0) ws[T1P_OFF + blk] = red[0];
        if (b == 0) {                                // blocks 0,1: c1 partials
            __syncthreads();
            red[tid] = log1pf(-p);
            __syncthreads();
            for (int s = 128; s > 0; s >>= 1) {
                if (tid < s) red[tid] += red[tid + s];
                __syncthreads();
            }
            if (tid == 0) ws[C1P_OFF + (blk & 1)] = red[0];
        }
        __syncthreads();
        if (tid == 0)
            __hip_atomic_store(&wsi[FLAG1_OFF + blk], MAGIC,
                               __ATOMIC_RELEASE, __HIP_MEMORY_SCOPE_AGENT);
    }

    // Preload phase-3 transpose tile (kwz is read-only input: no dependency).
    {
        const int c = tid & 63, r0 = tid >> 6;
        #pragma unroll
        for (int p2 = 0; p2 < 16; ++p2) {
            int rr = r0 + 4 * p2;
            ldsT[rr * 65 + c] = kwz[(size_t)(J * 64 + rr) * ND + (I * 64 + c)];
        }
    }

    // ---- Barrier A: wait for all 128 phase-1 blocks ----
    if (tid < 128) {
        while (__hip_atomic_load(&wsi[FLAG1_OFF + tid],
                                 __ATOMIC_ACQUIRE, __HIP_MEMORY_SCOPE_AGENT) != MAGIC) {}
    }
    __syncthreads();

    // ---------------- Phase 2: Q[e][f] = sum_b W[b][e] W[b][f], 32x32 tile ------
    const int e0 = I * 32, f0 = J * 32;
    for (int idx = tid; idx < 64 * 32; idx += 256) {
        int b2 = idx >> 5, col = idx & 31;
        We[idx] = ws[W_OFF + b2 * E + e0 + col];
        Wf[idx] = ws[W_OFF + b2 * E + f0 + col];
    }
    __syncthreads();
    {
        const int tf = tid & 31, teo = tid >> 5;    // teo 0..7
        float qa[4] = {0.f, 0.f, 0.f, 0.f};
        for (int b2 = 0; b2 < B; ++b2) {
            float wf = Wf[b2 * 32 + tf];
            #pragma unroll
            for (int r4 = 0; r4 < 4; ++r4)
                qa[r4] += We[b2 * 32 + teo + 8 * r4] * wf;
        }
        #pragma unroll
        for (int r4 = 0; r4 < 4; ++r4)
            ws[Q_OFF + (size_t)(e0 + teo + 8 * r4) * E + f0 + tf] = qa[r4];
    }
    __syncthreads();
    if (tid == 0)
        __hip_atomic_store(&wsi[FLAG2_OFF + blk], MAGIC,
                           __ATOMIC_RELEASE, __HIP_MEMORY_SCOPE_AGENT);

    // ---- Barrier B: wait for all 256 phase-2 blocks ----
    while (__hip_atomic_load(&wsi[FLAG2_OFF + tid],
                             __ATOMIC_ACQUIRE, __HIP_MEMORY_SCOPE_AGENT) != MAGIC) {}
    __syncthreads();

    // ---------------- Phase 3: t2 partial over 64x64 kwz tile -------------------
    {
        const int c = tid & 63, r0 = tid >> 6;
        float acc = 0.0f;
        #pragma unroll
        for (int p2 = 0; p2 < 16; ++p2) {
            int r = r0 + 4 * p2;
            int i = I * 64 + r;
            int j = J * 64 + c;
            float kij = kwz[(size_t)i * ND + j];                     // coalesced
            float kji = ldsT[c * 65 + r];                            // 2-way, free
            float q   = ws[Q_OFF + (size_t)(i >> 1) * E + (j >> 1)]; // pair-shared
            acc += kij * kji * q;
        }
        red[tid] = acc;
    }
    __syncthreads();
    for (int s = 128; s > 0; s >>= 1) {
        if (tid < s) red[tid] += red[tid + s];
        __syncthreads();
    }
    if (tid == 0) {
        ws[T2P_OFF + blk] = red[0];
        __hip_atomic_store(&wsi[FLAG3_OFF + blk], MAGIC,
                           __ATOMIC_RELEASE, __HIP_MEMORY_SCOPE_AGENT);
    }

    // ---------------- Finisher: block 0 assembles the loss ----------------------
    if (blk == 0) {
        while (__hip_atomic_load(&wsi[FLAG3_OFF + tid],
                                 __ATOMIC_ACQUIRE, __HIP_MEMORY_SCOPE_AGENT) != MAGIC) {}
        __syncthreads();
        float t2 = ws[T2P_OFF + tid];
        float t1 = (tid < 128) ? ws[T1P_OFF + tid] : 0.0f;
        float c1 = (tid < 2)   ? ws[C1P_OFF + tid] : 0.0f;
        // loss = -c1 + (0.5/B) * (t1 + 0.5*t2)
        red[tid] = (0.5f / (float)B) * (t1 + 0.5f * t2) - c1;
        __syncthreads();
        for (int s = 128; s > 0; s >>= 1) {
            if (tid < s) red[tid] += red[tid + s];
            __syncthreads();
        }
        if (tid == 0) out[0] = red[0];
    }
}

extern "C" void kernel_launch(void* const* d_in, const int* in_sizes, int n_in,
                              void* d_out, int out_size, void* d_ws, size_t ws_size,
                              hipStream_t stream) {
    const int*   det  = (const int*)d_in[0];    // [B, D]
    const int*   pebz = (const int*)d_in[1];    // [D, E]
    const float* para = (const float*)d_in[2];  // [E]
    const float* kwz  = (const float*)d_in[3];  // [ND, ND]
    // d_in[4] = edges_dict_z (arange(ND)//2, deterministic -> hardcoded)
    float* ws  = (float*)d_ws;
    float* out = (float*)d_out;

    hipLaunchKernelGGL(fused_k, dim3(256), dim3(256), 0, stream,
                       det, pebz, para, kwz, ws, out);
}

// Round 4
// 94.517 us; speedup vs baseline: 1.5352x; 1.5352x over previous
//
#include <hip/hip_runtime.h>
#include <math.h>

// Problem constants (fixed by the reference):
#define B  64
#define D  256
#define E  512
#define ND 1024

#define MAGIC 0x13579BDF

// ws offsets (4-byte units). Flags int; rest float. Poison 0xAAAAAAAA != MAGIC.
#define FLAG1_OFF 0       // [256] phase-A done flags
#define GO_OFF    320     // [1]   barrier release word
#define FLAG2_OFF 384     // [256] phase-B done flags
#define C1P_OFF   640     // [4]   c1 partials
#define T1P_OFF   704     // [256] t1 partials (per (b,quarter) slice)
#define T2P_OFF   960     // [256] t2 partials (per tile)
#define W_OFF     2048    // [B*E] signed undirected weights

__global__ __launch_bounds__(256) void fused_k(const int* __restrict__ det,
                                               const int* __restrict__ pebz,
                                               const float* __restrict__ para,
                                               const float* __restrict__ kwz,
                                               float* __restrict__ ws,
                                               float* __restrict__ out) {
    int* wsi = (int*)ws;
    const int blk = blockIdx.x;   // 0..255
    const int tid = threadIdx.x;  // 0..255

    __shared__ int   drow[D];            // 1 KB
    __shared__ int   pint[256];          // 1 KB
    __shared__ float red[256];           // 1 KB
    __shared__ float We[64 * 32];        // 8 KB
    __shared__ float Wf[64 * 32];        // 8 KB
    __shared__ float ldsQ[32 * 33];      // 4.1 KB (pad 33)
    __shared__ float ldsT[64 * 65];      // 16.6 KB (pad 65: 2-way, free per m136)

    // ================= Phase A: W slice + t1/c1 partials =================
    // Block owns (b = blk>>2, e-quarter q = blk&3). 2 threads per e over d-halves.
    const int b = blk >> 2, q = blk & 3;
    const int tl = tid & 127, dh = tid >> 7;
    const int e = q * 128 + tl;

    drow[tid] = det[b * D + tid];
    __syncthreads();

    float x = para[e];
    float p = 1.0f / (1.0f + expf(-x)) + 1e-20f;
    float w = p / (1.0f - p);

    int acc = 0;
    const int d0 = dh * 128;
    #pragma unroll 8
    for (int d = 0; d < 128; ++d)
        acc += drow[d0 + d] & pebz[(size_t)(d0 + d) * E + e];  // binary dot = AND
    pint[tid] = acc;
    __syncthreads();

    if (tid < 128) {
        int tot = pint[tid] + pint[tid + 128];
        float wbe = (tot & 1) ? -w : w;
        ws[W_OFF + b * E + e] = wbe;
        float dd = kwz[(size_t)(2 * e) * ND + (2 * e)]
                 + kwz[(size_t)(2 * e + 1) * ND + (2 * e + 1)];
        red[tid] = wbe * dd;
    } else {
        red[tid] = 0.0f;
    }
    __syncthreads();
    for (int s = 128; s > 0; s >>= 1) {
        if (tid < s) red[tid] += red[tid + s];
        __syncthreads();
    }
    if (tid == 0) ws[T1P_OFF + blk] = red[0];

    if (blk < 4) {   // b == 0 blocks: c1 partial over their e-slice
        red[tid] = (tid < 128) ? log1pf(-p) : 0.0f;
        __syncthreads();
        for (int s = 128; s > 0; s >>= 1) {
            if (tid < s) red[tid] += red[tid + s];
            __syncthreads();
        }
        if (tid == 0) ws[C1P_OFF + q] = red[0];
    }
    __syncthreads();

    if (tid == 0)
        __hip_atomic_store(&wsi[FLAG1_OFF + blk], MAGIC,
                           __ATOMIC_RELEASE, __HIP_MEMORY_SCOPE_AGENT);

    // ================= Barrier: block 0 collects, releases GO =================
    if (blk == 0) {
        while (__hip_atomic_load(&wsi[FLAG1_OFF + tid],
                                 __ATOMIC_ACQUIRE, __HIP_MEMORY_SCOPE_AGENT) != MAGIC)
            __builtin_amdgcn_s_sleep(2);
        __syncthreads();
        if (tid == 0)
            __hip_atomic_store(&wsi[GO_OFF], MAGIC,
                               __ATOMIC_RELEASE, __HIP_MEMORY_SCOPE_AGENT);
    }
    if (tid == 0) {   // 1 lane per block spins on 1 line, throttled
        while (__hip_atomic_load(&wsi[GO_OFF],
                                 __ATOMIC_ACQUIRE, __HIP_MEMORY_SCOPE_AGENT) != MAGIC)
            __builtin_amdgcn_s_sleep(16);
    }
    __syncthreads();

    // ================= Phase B: Q tile + local contraction =================
    // Tile (I,J): undirected e-range I*32.., f-range J*32..; directed 64x64.
    const int I = blk >> 4, J = blk & 15;
    const int e0 = I * 32, f0 = J * 32;

    for (int idx = tid; idx < 64 * 32; idx += 256) {
        int b2 = idx >> 5, col = idx & 31;
        We[idx] = ws[W_OFF + b2 * E + e0 + col];
        Wf[idx] = ws[W_OFF + b2 * E + f0 + col];
    }
    __syncthreads();

    {   // Q[e][f] tile: thread owns (teo+8*r4, tf), 4 entries
        const int tf = tid & 31, teo = tid >> 5;
        float qa[4] = {0.f, 0.f, 0.f, 0.f};
        for (int b2 = 0; b2 < B; ++b2) {
            float wf = Wf[b2 * 32 + tf];
            #pragma unroll
            for (int r4 = 0; r4 < 4; ++r4)
                qa[r4] += We[b2 * 32 + teo + 8 * r4] * wf;
        }
        #pragma unroll
        for (int r4 = 0; r4 < 4; ++r4)
            ldsQ[(teo + 8 * r4) * 33 + tf] = qa[r4];
    }
    {   // transpose-source tile for K_ji
        const int c = tid & 63, r0 = tid >> 6;
        #pragma unroll
        for (int p2 = 0; p2 < 16; ++p2) {
            int rr = r0 + 4 * p2;
            ldsT[rr * 65 + c] = kwz[(size_t)(J * 64 + rr) * ND + (I * 64 + c)];
        }
    }
    __syncthreads();

    {   // t2 partial = sum over tile of K_ij * K_ji * Q[i/2][j/2]
        const int c = tid & 63, r0 = tid >> 6;
        float acc2 = 0.0f;
        #pragma unroll
        for (int p2 = 0; p2 < 16; ++p2) {
            int r = r0 + 4 * p2;
            float kij = kwz[(size_t)(I * 64 + r) * ND + (J * 64 + c)]; // coalesced
            float kji = ldsT[c * 65 + r];                              // bank-clean
            float qv  = ldsQ[(r >> 1) * 33 + (c >> 1)];                // pair-broadcast
            acc2 += kij * kji * qv;
        }
        red[tid] = acc2;
    }
    __syncthreads();
    for (int s = 128; s > 0; s >>= 1) {
        if (tid < s) red[tid] += red[tid + s];
        __syncthreads();
    }
    if (tid == 0) {
        ws[T2P_OFF + blk] = red[0];
        __hip_atomic_store(&wsi[FLAG2_OFF + blk], MAGIC,
                           __ATOMIC_RELEASE, __HIP_MEMORY_SCOPE_AGENT);
    }

    // ================= Tail: block 0 assembles the loss =================
    if (blk == 0) {
        while (__hip_atomic_load(&wsi[FLAG2_OFF + tid],
                                 __ATOMIC_ACQUIRE, __HIP_MEMORY_SCOPE_AGENT) != MAGIC)
            __builtin_amdgcn_s_sleep(2);
        __syncthreads();
        // loss = -c1 + (0.5/B)*t1 + (0.25/B)*t2
        float t1 = ws[T1P_OFF + tid];
        float t2 = ws[T2P_OFF + tid];
        float c1 = (tid < 4) ? ws[C1P_OFF + tid] : 0.0f;
        red[tid] = (0.5f / (float)B) * t1 + (0.25f / (float)B) * t2 - c1;
        __syncthreads();
        for (int s = 128; s > 0; s >>= 1) {
            if (tid < s) red[tid] += red[tid + s];
            __syncthreads();
        }
        if (tid == 0) out[0] = red[0];
    }
}

extern "C" void kernel_launch(void* const* d_in, const int* in_sizes, int n_in,
                              void* d_out, int out_size, void* d_ws, size_t ws_size,
                              hipStream_t stream) {
    const int*   det  = (const int*)d_in[0];    // [B, D]
    const int*   pebz = (const int*)d_in[1];    // [D, E]
    const float* para = (const float*)d_in[2];  // [E]
    const float* kwz  = (const float*)d_in[3];  // [ND, ND]
    // d_in[4] = edges_dict_z (arange(ND)//2, deterministic -> hardcoded)
    float* ws  = (float*)d_ws;
    float* out = (float*)d_out;

    hipLaunchKernelGGL(fused_k, dim3(256), dim3(256), 0, stream,
                       det, pebz, para, kwz, ws, out);
}